// Round 1
// baseline (66.441 us; speedup 1.0000x reference)
//
#include <hip/hip_runtime.h>
#include <math.h>

// ---------------- complex helpers (f32) ----------------
struct cplx { float re, im; };

__device__ __forceinline__ cplx cmul(cplx a, cplx b) {
    return {a.re*b.re - a.im*b.im, a.re*b.im + a.im*b.re};
}
__device__ __forceinline__ cplx cadd(cplx a, cplx b){ return {a.re+b.re, a.im+b.im}; }
__device__ __forceinline__ cplx csub(cplx a, cplx b){ return {a.re-b.re, a.im-b.im}; }
__device__ __forceinline__ cplx cscale(cplx a, float s){ return {a.re*s, a.im*s}; }
__device__ __forceinline__ cplx cinv(cplx a) {
    float d = 1.0f/(a.re*a.re + a.im*a.im);
    return {a.re*d, -a.im*d};
}
__device__ __forceinline__ cplx cdiv(cplx a, cplx b){ return cmul(a, cinv(b)); }
// principal-branch complex sqrt
__device__ __forceinline__ cplx csqrtc(cplx z) {
    float r = sqrtf(z.re*z.re + z.im*z.im);
    float u = sqrtf(0.5f*fmaxf(r + z.re, 0.0f));
    float v = sqrtf(0.5f*fmaxf(r - z.re, 0.0f));
    v = (z.im < 0.0f) ? -v : v;
    return {u, v};
}

// ---------------- stage 1: n(layer, lambda) interpolation ----------------
__global__ void interp_kernel(const float* __restrict__ wavelengths,
                              const float* __restrict__ fixed_data,
                              const float* __restrict__ dyn_wl,
                              const float* __restrict__ ri,
                              const float* __restrict__ ec,
                              const int*   __restrict__ matdist,
                              float2* __restrict__ nbuf,
                              int NL, int W, int P, int nFixed)
{
    int tid = blockIdx.x*blockDim.x + threadIdx.x;
    if (tid >= NL*W) return;
    int l = tid / W;
    int w = tid - l*W;
    float x = wavelengths[w];
    int mat = matdist[l];
    const float *xp, *fn, *fk;
    if (mat < nFixed) {
        xp = fixed_data + (size_t)mat*3*P;
        fn = xp + P;
        fk = xp + 2*P;
    } else {
        xp = dyn_wl; fn = ri; fk = ec;
    }
    float nr, nk;
    if (x <= xp[0])            { nr = fn[0];   nk = fk[0]; }
    else if (x >= xp[P-1])     { nr = fn[P-1]; nk = fk[P-1]; }
    else {
        int lo = 0, hi = P-1;
        while (hi - lo > 1) {
            int mid = (lo + hi) >> 1;
            if (xp[mid] <= x) lo = mid; else hi = mid;
        }
        float t = (x - xp[lo]) / (xp[lo+1] - xp[lo]);
        nr = fn[lo] + t*(fn[lo+1] - fn[lo]);
        nk = fk[lo] + t*(fk[lo+1] - fk[lo]);
    }
    nbuf[tid] = make_float2(nr, nk);
}

// ---------------- stage 2: TMM per (angle, wavelength) ----------------
__global__ void __launch_bounds__(256)
tmm_kernel(const float2* __restrict__ nbuf,
           const float*  __restrict__ wavelengths,
           const float*  __restrict__ angles,
           const float*  __restrict__ th_above,
           const float*  __restrict__ th_unk,
           const float*  __restrict__ th_below,
           float* __restrict__ out,
           int NL, int W, int A, int nAbove)
{
    int idx = blockIdx.x*blockDim.x + threadIdx.x;
    int total = A*W;
    if (idx >= total) return;
    int w = idx % W;
    int a = idx / W;

    float lam = wavelengths[w];
    float ang = angles[a];
    float s0  = sinf(ang);
    float k0  = 6.28318530717958647692f / lam;   // 2*pi/lambda

    // layer 0
    float2 v0 = nbuf[w];
    cplx n0 = {v0.x, v0.y};
    cplx ns = cscale(n0, s0);                    // n0 * sin0 (numerator for all layers)

    auto layer_cos = [&](cplx nj) -> cplx {
        cplx sj = cdiv(ns, nj);
        cplx s2 = cmul(sj, sj);
        cplx one_m = {1.0f - s2.re, -s2.im};
        return csqrtc(one_m);
    };

    cplx n_prev = n0;
    cplx c_prev = layer_cos(n0);
    cplx nfirst = n_prev, cfirst = c_prev;

    cplx ms00, ms01, ms10, ms11;
    cplx mp00, mp01, mp10, mp11;

    for (int i = 0; i < NL-1; ++i) {
        float2 vc = nbuf[(size_t)(i+1)*W + w];
        cplx n_cur = {vc.x, vc.y};
        cplx c_cur = layer_cos(n_cur);

        // Fresnel at interface i (between layer i and i+1)
        cplx nici = cmul(n_prev, c_prev);
        cplx njcj = cmul(n_cur,  c_cur);
        cplx nicj = cmul(n_prev, c_cur);
        cplx njci = cmul(n_cur,  c_prev);

        // s-pol
        cplx dens  = cadd(nici, njcj);
        cplx idens = cinv(dens);
        cplx rs = cmul(csub(nici, njcj), idens);
        cplx ts = cmul(cscale(nici, 2.0f), idens);
        // p-pol
        cplx denp  = cadd(njci, nicj);
        cplx idenp = cinv(denp);
        cplx rp = cmul(csub(njci, nicj), idenp);
        cplx tp = cmul(cscale(nici, 2.0f), idenp);

        if (i == 0) {
            cplx its = cinv(ts);
            ms00 = its; ms11 = its;
            ms01 = cmul(rs, its); ms10 = ms01;
            cplx itp = cinv(tp);
            mp00 = itp; mp11 = itp;
            mp01 = cmul(rp, itp); mp10 = mp01;
        } else {
            // delta for layer i (uses n_prev*c_prev = nici), thickness index i-1
            int j = i - 1;
            float th;
            if (j < nAbove)        th = th_above[j];
            else if (j == nAbove)  th = th_unk[0] * 0.001f;
            else                   th = th_below[j - nAbove - 1];

            cplx dlt = cscale(nici, k0 * th);
            float edi  = expf(dlt.im);
            float emdi = expf(-dlt.im);
            float sdr, cdr;
            sincosf(dlt.re, &sdr, &cdr);
            cplx em = { edi*cdr, -edi*sdr};   // exp(-i*d)
            cplx ep = {emdi*cdr,  emdi*sdr};  // exp(+i*d)

            // s-pol update
            {
                cplx it  = cinv(ts);
                cplx a00 = cmul(em, it);
                cplx a11 = cmul(ep, it);
                cplx a01 = cmul(a00, rs);
                cplx a10 = cmul(a11, rs);
                cplx t00 = cadd(cmul(ms00,a00), cmul(ms01,a10));
                cplx t01 = cadd(cmul(ms00,a01), cmul(ms01,a11));
                cplx t10 = cadd(cmul(ms10,a00), cmul(ms11,a10));
                cplx t11 = cadd(cmul(ms10,a01), cmul(ms11,a11));
                ms00=t00; ms01=t01; ms10=t10; ms11=t11;
            }
            // p-pol update
            {
                cplx it  = cinv(tp);
                cplx a00 = cmul(em, it);
                cplx a11 = cmul(ep, it);
                cplx a01 = cmul(a00, rp);
                cplx a10 = cmul(a11, rp);
                cplx t00 = cadd(cmul(mp00,a00), cmul(mp01,a10));
                cplx t01 = cadd(cmul(mp00,a01), cmul(mp01,a11));
                cplx t10 = cadd(cmul(mp10,a00), cmul(mp11,a10));
                cplx t11 = cadd(cmul(mp10,a01), cmul(mp11,a11));
                mp00=t00; mp01=t01; mp10=t10; mp11=t11;
            }
        }
        n_prev = n_cur;
        c_prev = c_cur;
    }

    // epilogue: R, T, A
    float inv_m00s = 1.0f/(ms00.re*ms00.re + ms00.im*ms00.im);
    float Rs = (ms10.re*ms10.re + ms10.im*ms10.im) * inv_m00s;
    float fac_s = (n_prev.re*c_prev.re - n_prev.im*c_prev.im) /
                  (nfirst.re*cfirst.re - nfirst.im*cfirst.im);
    float Ts = inv_m00s * fac_s;

    float inv_m00p = 1.0f/(mp00.re*mp00.re + mp00.im*mp00.im);
    float Rp = (mp10.re*mp10.re + mp10.im*mp10.im) * inv_m00p;
    float fac_p = (n_prev.re*c_prev.re + n_prev.im*c_prev.im) /
                  (nfirst.re*cfirst.re + nfirst.im*cfirst.im);
    float Tp = inv_m00p * fac_p;

    float R = 0.5f*(Rs + Rp);
    float T = 0.5f*(Ts + Tp);

    size_t plane = (size_t)A * (size_t)W;
    out[idx]           = R;
    out[plane + idx]   = T;
    out[2*plane + idx] = 1.0f - R - T;
}

extern "C" void kernel_launch(void* const* d_in, const int* in_sizes, int n_in,
                              void* d_out, int out_size, void* d_ws, size_t ws_size,
                              hipStream_t stream) {
    const float* ri          = (const float*)d_in[0];
    const float* ec          = (const float*)d_in[1];
    const float* unk         = (const float*)d_in[2];
    const float* fixed_data  = (const float*)d_in[3];
    const float* dyn_wl      = (const float*)d_in[4];
    const int*   matdist     = (const int*)  d_in[5];
    const float* th_above    = (const float*)d_in[6];
    const float* th_below    = (const float*)d_in[7];
    const float* wavelengths = (const float*)d_in[8];
    const float* angles      = (const float*)d_in[9];

    int P      = in_sizes[0];
    int NL     = in_sizes[5];
    int nAbove = in_sizes[6];
    int W      = in_sizes[8];
    int A      = in_sizes[9];
    int nFixed = in_sizes[3] / (3*P);

    float2* nbuf = (float2*)d_ws;   // [NL][W] complex n

    int tot1 = NL*W;
    interp_kernel<<<(tot1+255)/256, 256, 0, stream>>>(
        wavelengths, fixed_data, dyn_wl, ri, ec, matdist, nbuf, NL, W, P, nFixed);

    int tot2 = A*W;
    tmm_kernel<<<(tot2+255)/256, 256, 0, stream>>>(
        nbuf, wavelengths, angles, th_above, unk, th_below,
        (float*)d_out, NL, W, A, nAbove);
}

// Round 2
// 37.519 us; speedup vs baseline: 1.7709x; 1.7709x over previous
//
#include <hip/hip_runtime.h>
#include <math.h>

// ---------------- complex helpers (f32) ----------------
struct cplx { float re, im; };

__device__ __forceinline__ float frcp(float x){ return __builtin_amdgcn_rcpf(x); }
__device__ __forceinline__ cplx cmul(cplx a, cplx b) {
    return {a.re*b.re - a.im*b.im, a.re*b.im + a.im*b.re};
}
__device__ __forceinline__ cplx cadd(cplx a, cplx b){ return {a.re+b.re, a.im+b.im}; }
__device__ __forceinline__ cplx csub(cplx a, cplx b){ return {a.re-b.re, a.im-b.im}; }
__device__ __forceinline__ float cabs2(cplx a){ return a.re*a.re + a.im*a.im; }
// principal-branch complex sqrt
__device__ __forceinline__ cplx csqrtc(cplx z) {
    float r = sqrtf(z.re*z.re + z.im*z.im);
    float u = sqrtf(0.5f*fmaxf(r + z.re, 0.0f));
    float v = sqrtf(0.5f*fmaxf(r - z.re, 0.0f));
    v = (z.im < 0.0f) ? -v : v;
    return {u, v};
}

// ---------------- stage 1: n(layer, lambda) + 1/n^2 ----------------
__global__ void interp_kernel(const float* __restrict__ wavelengths,
                              const float* __restrict__ fixed_data,
                              const float* __restrict__ dyn_wl,
                              const float* __restrict__ ri,
                              const float* __restrict__ ec,
                              const int*   __restrict__ matdist,
                              float4* __restrict__ nbuf,
                              int NL, int W, int P, int nFixed)
{
    int tid = blockIdx.x*blockDim.x + threadIdx.x;
    if (tid >= NL*W) return;
    int l = tid / W;
    int w = tid - l*W;
    float x = wavelengths[w];
    int mat = matdist[l];
    const float *xp, *fn, *fk;
    if (mat < nFixed) {
        xp = fixed_data + (size_t)mat*3*P;
        fn = xp + P;
        fk = xp + 2*P;
    } else {
        xp = dyn_wl; fn = ri; fk = ec;
    }
    float nr, nk;
    if (x <= xp[0])            { nr = fn[0];   nk = fk[0]; }
    else if (x >= xp[P-1])     { nr = fn[P-1]; nk = fk[P-1]; }
    else {
        int lo = 0, hi = P-1;
        while (hi - lo > 1) {
            int mid = (lo + hi) >> 1;
            if (xp[mid] <= x) lo = mid; else hi = mid;
        }
        float t = (x - xp[lo]) / (xp[lo+1] - xp[lo]);
        nr = fn[lo] + t*(fn[lo+1] - fn[lo]);
        nk = fk[lo] + t*(fk[lo+1] - fk[lo]);
    }
    // inv n^2 (precise path, runs once per (layer, lambda))
    cplx n  = {nr, nk};
    cplx n2 = cmul(n, n);
    float d = 1.0f / (n2.re*n2.re + n2.im*n2.im);
    nbuf[tid] = make_float4(nr, nk, n2.re*d, -n2.im*d);
}

// ---------------- stage 2: TMM per (angle, wavelength) ----------------
// Reverse-order matrix-vector chain: F[:,0] = M0 * A1 * ... * A_{NL-2} * e0.
// |t| factors accumulated as a real product (they cancel in r, appear only in T).
template<int NLC>
__global__ void __launch_bounds__(256)
tmm_fast(const float4* __restrict__ nbuf,
         const float*  __restrict__ wavelengths,
         const float*  __restrict__ angles,
         const float*  __restrict__ th_above,
         const float*  __restrict__ th_unk,
         const float*  __restrict__ th_below,
         float* __restrict__ out,
         int NLrt, int W, int A, int nAbove)
{
    const int NL = (NLC > 0) ? NLC : NLrt;
    int idx = blockIdx.x*blockDim.x + threadIdx.x;
    int total = A*W;
    if (idx >= total) return;
    int w = idx % W;
    int a = idx / W;

    float lam = wavelengths[w];
    float s0  = __sinf(angles[a]);
    float k0  = 6.28318530717958647692f * frcp(lam);

    // ambient n0, common (n0*sin0)^2
    float4 v0l = nbuf[w];
    cplx n0 = {v0l.x, v0l.y};
    cplx ns = {n0.re*s0, n0.im*s0};
    cplx ns2 = cmul(ns, ns);

    // start from top layer (substrate) NL-1
    float4 vt = nbuf[(size_t)(NL-1)*W + w];
    cplx n_u = {vt.x, vt.y};
    {
    }
    cplx tq  = cmul(ns2, {vt.z, vt.w});
    cplx c_u = csqrtc({1.0f - tq.re, -tq.im});
    cplx nucu = cmul(n_u, c_u);

    // transmission factor numerators (substrate side)
    float fs_num = nucu.re;                              // Re(n*c)
    float fp_num = n_u.re*c_u.re + n_u.im*c_u.im;        // Re(n*conj(c))
    float fs_den = 1.0f, fp_den = 1.0f;

    cplx vs0 = {1.0f, 0.0f}, vs1 = {0.0f, 0.0f};
    cplx vp0 = {1.0f, 0.0f}, vp1 = {0.0f, 0.0f};
    float tsq_s = 1.0f, tsq_p = 1.0f;

    #pragma unroll
    for (int i = NL-2; i >= 0; --i) {
        float4 vl = nbuf[(size_t)i*W + w];
        cplx n_l = {vl.x, vl.y};
        cplx t2  = cmul(ns2, {vl.z, vl.w});
        cplx c_l = csqrtc({1.0f - t2.re, -t2.im});

        cplx nlcl = cmul(n_l, c_l);
        cplx nucl = cmul(n_u, c_l);
        cplx nlcu = cmul(n_l, c_u);

        float nlcl2 = cabs2(nlcl);

        // s-pol: den = nlcl + nucu ; r = (nlcl - nucu)/den ; |t|^2 = 4|nlcl|^2/|den|^2
        cplx dens  = cadd(nlcl, nucu);
        float ids  = frcp(cabs2(dens));
        cplx dfs   = csub(nlcl, nucu);
        cplx rs = { (dfs.re*dens.re + dfs.im*dens.im)*ids,
                    (dfs.im*dens.re - dfs.re*dens.im)*ids };
        tsq_s *= 4.0f * nlcl2 * ids;

        // p-pol: den = nucl + nlcu ; r = (nucl - nlcu)/den ; |t|^2 = 4|nlcl|^2/|den|^2
        cplx denp  = cadd(nucl, nlcu);
        float idp  = frcp(cabs2(denp));
        cplx dfp   = csub(nucl, nlcu);
        cplx rp = { (dfp.re*denp.re + dfp.im*denp.im)*idp,
                    (dfp.im*denp.re - dfp.re*denp.im)*idp };
        tsq_p *= 4.0f * nlcl2 * idp;

        if (i >= 1) {
            // phase of layer i (lower layer), thickness index i-1
            int j = i - 1;
            float th;
            if (j < nAbove)        th = th_above[j];
            else if (j == nAbove)  th = th_unk[0] * 0.001f;
            else                   th = th_below[j - nAbove - 1];
            float kd = k0 * th;
            float dr = kd * nlcl.re;
            float di = kd * nlcl.im;
            float edi  = __expf(di);
            float emdi = frcp(edi);
            float sdr, cdr;
            __sincosf(dr, &sdr, &cdr);
            cplx em = { edi*cdr, -edi*sdr };    // exp(-i*delta)
            cplx ep = { emdi*cdr, emdi*sdr };   // exp(+i*delta)

            cplx u0 = cadd(vs0, cmul(rs, vs1));
            cplx u1 = cadd(cmul(rs, vs0), vs1);
            vs0 = cmul(em, u0); vs1 = cmul(ep, u1);

            cplx w0 = cadd(vp0, cmul(rp, vp1));
            cplx w1 = cadd(cmul(rp, vp0), vp1);
            vp0 = cmul(em, w0); vp1 = cmul(ep, w1);
        } else {
            // interface 0: no propagation phase
            cplx u0 = cadd(vs0, cmul(rs, vs1));
            cplx u1 = cadd(cmul(rs, vs0), vs1);
            vs0 = u0; vs1 = u1;
            cplx w0 = cadd(vp0, cmul(rp, vp1));
            cplx w1 = cadd(cmul(rp, vp0), vp1);
            vp0 = w0; vp1 = w1;
            fs_den = nlcl.re;
            fp_den = n_l.re*c_l.re + n_l.im*c_l.im;
        }
        n_u = n_l; c_u = c_l; nucu = nlcl;
    }

    float iv0s = frcp(cabs2(vs0));
    float Rs = cabs2(vs1) * iv0s;
    float Ts = tsq_s * iv0s * fs_num * frcp(fs_den);

    float iv0p = frcp(cabs2(vp0));
    float Rp = cabs2(vp1) * iv0p;
    float Tp = tsq_p * iv0p * fp_num * frcp(fp_den);

    float R = 0.5f*(Rs + Rp);
    float T = 0.5f*(Ts + Tp);

    size_t plane = (size_t)A * (size_t)W;
    out[idx]           = R;
    out[plane + idx]   = T;
    out[2*plane + idx] = 1.0f - R - T;
}

extern "C" void kernel_launch(void* const* d_in, const int* in_sizes, int n_in,
                              void* d_out, int out_size, void* d_ws, size_t ws_size,
                              hipStream_t stream) {
    const float* ri          = (const float*)d_in[0];
    const float* ec          = (const float*)d_in[1];
    const float* unk         = (const float*)d_in[2];
    const float* fixed_data  = (const float*)d_in[3];
    const float* dyn_wl      = (const float*)d_in[4];
    const int*   matdist     = (const int*)  d_in[5];
    const float* th_above    = (const float*)d_in[6];
    const float* th_below    = (const float*)d_in[7];
    const float* wavelengths = (const float*)d_in[8];
    const float* angles      = (const float*)d_in[9];

    int P      = in_sizes[0];
    int NL     = in_sizes[5];
    int nAbove = in_sizes[6];
    int W      = in_sizes[8];
    int A      = in_sizes[9];
    int nFixed = in_sizes[3] / (3*P);

    float4* nbuf = (float4*)d_ws;   // [NL][W] {n.re, n.im, invn2.re, invn2.im}

    int tot1 = NL*W;
    interp_kernel<<<(tot1+255)/256, 256, 0, stream>>>(
        wavelengths, fixed_data, dyn_wl, ri, ec, matdist, nbuf, NL, W, P, nFixed);

    int tot2 = A*W;
    int blocks = (tot2+255)/256;
    if (NL == 13) {
        tmm_fast<13><<<blocks, 256, 0, stream>>>(
            nbuf, wavelengths, angles, th_above, unk, th_below,
            (float*)d_out, NL, W, A, nAbove);
    } else {
        tmm_fast<0><<<blocks, 256, 0, stream>>>(
            nbuf, wavelengths, angles, th_above, unk, th_below,
            (float*)d_out, NL, W, A, nAbove);
    }
}

// Round 4
// 28.808 us; speedup vs baseline: 2.3063x; 1.3024x over previous
//
#include <hip/hip_runtime.h>
#include <math.h>

typedef float v2f __attribute__((ext_vector_type(2)));

struct cplx { float re, im; };
struct pcplx { v2f re, im; };   // pol-packed complex: lane 0 = s, lane 1 = p

__device__ __forceinline__ float frcp(float x){ return __builtin_amdgcn_rcpf(x); }
__device__ __forceinline__ cplx cmul(cplx a, cplx b){
    return {a.re*b.re - a.im*b.im, a.re*b.im + a.im*b.re};
}
__device__ __forceinline__ float cabs2(cplx a){ return a.re*a.re + a.im*a.im; }
__device__ __forceinline__ v2f mk2(float a, float b){ v2f r; r.x = a; r.y = b; return r; }

// principal sqrt, valid for Re(z) > 0 (holds here: Re(n^2 - ns^2) >= ~0.25)
__device__ __forceinline__ cplx csqrt_rhp(cplx z){
    float r = sqrtf(z.re*z.re + z.im*z.im);
    float u = sqrtf(0.5f*(r + z.re));
    float v = 0.5f*z.im*frcp(u);
    return {u, v};
}

// ---------------- stage 1: per (layer, lambda): n^2, |n|^2 ; plus 4*pi*th table ----
__global__ void interp_kernel(const float* __restrict__ wavelengths,
                              const float* __restrict__ fixed_data,
                              const float* __restrict__ dyn_wl,
                              const float* __restrict__ ri,
                              const float* __restrict__ ec,
                              const int*   __restrict__ matdist,
                              const float* __restrict__ th_above,
                              const float* __restrict__ th_unk,
                              const float* __restrict__ th_below,
                              float4* __restrict__ nbuf,
                              float*  __restrict__ tk,
                              int NL, int W, int P, int nFixed, int nAbove)
{
    int tid = blockIdx.x*blockDim.x + threadIdx.x;
    if (tid < NL-2) {
        float th;
        if (tid < nAbove)        th = th_above[tid];
        else if (tid == nAbove)  th = th_unk[0] * 0.001f;
        else                     th = th_below[tid - nAbove - 1];
        tk[tid] = 12.5663706143591729539f * th;   // 4*pi*th  (for 2*delta phase)
    }
    if (tid >= NL*W) return;
    int l = tid / W;
    int w = tid - l*W;
    float x = wavelengths[w];
    int mat = matdist[l];
    const float *xp, *fn, *fk;
    if (mat < nFixed) {
        xp = fixed_data + (size_t)mat*3*P;
        fn = xp + P;
        fk = xp + 2*P;
    } else {
        xp = dyn_wl; fn = ri; fk = ec;
    }
    float nr, nk;
    if (x <= xp[0])            { nr = fn[0];   nk = fk[0]; }
    else if (x >= xp[P-1])     { nr = fn[P-1]; nk = fk[P-1]; }
    else {
        int lo = 0, hi = P-1;
        while (hi - lo > 1) {
            int mid = (lo + hi) >> 1;
            if (xp[mid] <= x) lo = mid; else hi = mid;
        }
        float t = (x - xp[lo]) / (xp[lo+1] - xp[lo]);
        nr = fn[lo] + t*(fn[lo+1] - fn[lo]);
        nk = fk[lo] + t*(fk[lo+1] - fk[lo]);
    }
    // n^2 (complex) and |n|^2
    float n2re = nr*nr - nk*nk;
    float n2im = 2.0f*nr*nk;
    float nn2  = nr*nr + nk*nk;
    nbuf[tid] = make_float4(n2re, n2im, nn2, 0.0f);
}

// ---------------- stage 2: TMM, kz-form, unnormalized pol-packed chain ------------
// q_j = n_j cos_j = principal sqrt(n_j^2 - (n0 sin0)^2)
// s:  den = q_l + q_u,             df = q_l - q_u,             |t|^2*|den|^2 = 4|q_l|^2
// p:  den = n_u^2 q_l + n_l^2 q_u, df = n_u^2 q_l - n_l^2 q_u, |t|^2*|den|^2 = 4|q_l|^2 |n_l|^2 |n_u|^2
// chain (unnormalized, alpha-scaled): u0 = den*v0 + df*v1 ; u1 = df*v0 + den*v1
// phase (ep factored out): v0 = e^{-2i delta} u0 ; v1 = u1 ;
//   T recovery: tsq *= f * e^{+2 Im(delta)}   (ep enters m00 as multiplier -> divide |ep|^2)
template<int NLC>
__global__ void __launch_bounds__(256)
tmm_fast(const float4* __restrict__ nbuf,
         const float*  __restrict__ tk,
         const float*  __restrict__ wavelengths,
         const float*  __restrict__ angles,
         float* __restrict__ out,
         int NLrt, int W, int A)
{
    const int NL = (NLC > 0) ? NLC : NLrt;
    int idx = blockIdx.x*blockDim.x + threadIdx.x;
    int total = A*W;
    if (idx >= total) return;
    int w = idx % W;
    int a = idx / W;

    float ilam = frcp(wavelengths[w]);
    float s0   = __sinf(angles[a]);
    float s02  = s0*s0;

    // ambient (layer 0) n^2 -> ns2 = (n0 sin0)^2
    float4 vamb = nbuf[w];
    cplx ns2 = { vamb.x*s02, vamb.y*s02 };

    // substrate (layer NL-1)
    float4 vt = nbuf[(size_t)(NL-1)*W + w];
    cplx n2_u = {vt.x, vt.y};
    float nn2_u = vt.z;
    cplx q_u = csqrt_rhp({n2_u.re - ns2.re, n2_u.im - ns2.im});
    float fs_num = q_u.re;
    float fp_num = (n2_u.re*q_u.re + n2_u.im*q_u.im) * frcp(nn2_u);

    pcplx v0; v0.re = mk2(1.f, 1.f); v0.im = mk2(0.f, 0.f);
    pcplx v1; v1.re = mk2(0.f, 0.f); v1.im = mk2(0.f, 0.f);
    v2f tsq = mk2(1.f, 1.f);
    float fs_den = 1.f, fp_den = 1.f;

    const float AS = 0.5f,  AP = 0.125f;       // range-control scales
    const float CS = 4.f*AS*AS, CP = 4.f*AP*AP;

    #pragma unroll
    for (int i = NL-2; i >= 0; --i) {
        float4 vl = nbuf[(size_t)i*W + w];
        cplx n2_l = {vl.x, vl.y};
        float nn2_l = vl.z;
        cplx q_l = csqrt_rhp({n2_l.re - ns2.re, n2_l.im - ns2.im});
        float aq2 = cabs2(q_l);

        cplx Ac = cmul(n2_u, q_l);
        cplx Bc = cmul(n2_l, q_u);

        pcplx den, dff;
        den.re = mk2(AS*(q_l.re + q_u.re), AP*(Ac.re + Bc.re));
        den.im = mk2(AS*(q_l.im + q_u.im), AP*(Ac.im + Bc.im));
        dff.re = mk2(AS*(q_l.re - q_u.re), AP*(Ac.re - Bc.re));
        dff.im = mk2(AS*(q_l.im - q_u.im), AP*(Ac.im - Bc.im));

        v2f f = mk2(CS*aq2, CP*aq2*nn2_l*nn2_u);

        pcplx u0, u1;
        u0.re = den.re*v0.re - den.im*v0.im + dff.re*v1.re - dff.im*v1.im;
        u0.im = den.re*v0.im + den.im*v0.re + dff.re*v1.im + dff.im*v1.re;
        u1.re = dff.re*v0.re - dff.im*v0.im + den.re*v1.re - den.im*v1.im;
        u1.im = dff.re*v0.im + dff.im*v0.re + den.re*v1.im + den.im*v1.re;

        if (i >= 1) {
            float kd2 = tk[i-1]*ilam;          // 2 * k0 * th
            float dr2 = kd2*q_l.re;            // 2 Re(delta)
            float di2 = kd2*q_l.im;            // 2 Im(delta)
            float e2  = __expf(di2);           // e^{+2 Im delta} = 1/|ep|^2
            float s2, c2;
            __sincosf(dr2, &s2, &c2);
            float pr = e2*c2, pi = -e2*s2;     // e^{-2 i delta}
            v0.re = pr*u0.re - pi*u0.im;
            v0.im = pr*u0.im + pi*u0.re;
            v1 = u1;
            tsq = tsq * (f*e2);                // FIX: multiply by e2 (divide by |ep|^2)
        } else {
            v0 = u0; v1 = u1;
            tsq = tsq * f;
            fs_den = q_l.re;
            fp_den = (n2_l.re*q_l.re + n2_l.im*q_l.im)*frcp(nn2_l);
        }
        n2_u = n2_l; nn2_u = nn2_l; q_u = q_l;
    }

    v2f m0 = v0.re*v0.re + v0.im*v0.im;
    v2f m1 = v1.re*v1.re + v1.im*v1.im;
    v2f iv0 = mk2(frcp(m0.x), frcp(m0.y));
    v2f Rv = m1*iv0;
    v2f fac = mk2(fs_num*frcp(fs_den), fp_num*frcp(fp_den));
    v2f Tv = tsq*iv0*fac;

    float R = 0.5f*(Rv.x + Rv.y);
    float T = 0.5f*(Tv.x + Tv.y);

    size_t plane = (size_t)A * (size_t)W;
    out[idx]           = R;
    out[plane + idx]   = T;
    out[2*plane + idx] = 1.0f - R - T;
}

extern "C" void kernel_launch(void* const* d_in, const int* in_sizes, int n_in,
                              void* d_out, int out_size, void* d_ws, size_t ws_size,
                              hipStream_t stream) {
    const float* ri          = (const float*)d_in[0];
    const float* ec          = (const float*)d_in[1];
    const float* unk         = (const float*)d_in[2];
    const float* fixed_data  = (const float*)d_in[3];
    const float* dyn_wl      = (const float*)d_in[4];
    const int*   matdist     = (const int*)  d_in[5];
    const float* th_above    = (const float*)d_in[6];
    const float* th_below    = (const float*)d_in[7];
    const float* wavelengths = (const float*)d_in[8];
    const float* angles      = (const float*)d_in[9];

    int P      = in_sizes[0];
    int NL     = in_sizes[5];
    int nAbove = in_sizes[6];
    int W      = in_sizes[8];
    int A      = in_sizes[9];
    int nFixed = in_sizes[3] / (3*P);

    float4* nbuf = (float4*)d_ws;                       // [NL][W] {n2.re, n2.im, |n|^2, 0}
    float*  tk   = (float*)((char*)d_ws + (size_t)NL*W*sizeof(float4));  // [NL-2] 4*pi*th

    int tot1 = NL*W;
    interp_kernel<<<(tot1+255)/256, 256, 0, stream>>>(
        wavelengths, fixed_data, dyn_wl, ri, ec, matdist,
        th_above, unk, th_below, nbuf, tk, NL, W, P, nFixed, nAbove);

    int tot2 = A*W;
    int blocks = (tot2+255)/256;
    if (NL == 13) {
        tmm_fast<13><<<blocks, 256, 0, stream>>>(
            nbuf, tk, wavelengths, angles, (float*)d_out, NL, W, A);
    } else {
        tmm_fast<0><<<blocks, 256, 0, stream>>>(
            nbuf, tk, wavelengths, angles, (float*)d_out, NL, W, A);
    }
}

// Round 5
// 26.498 us; speedup vs baseline: 2.5074x; 1.0872x over previous
//
#include <hip/hip_runtime.h>
#include <math.h>

typedef float v2f __attribute__((ext_vector_type(2)));

struct cplx { float re, im; };
struct pcplx { v2f re, im; };   // pol-packed complex: lane 0 = s, lane 1 = p

__device__ __forceinline__ float frcp(float x){ return __builtin_amdgcn_rcpf(x); }
__device__ __forceinline__ float frsq(float x){ return __builtin_amdgcn_rsqf(x); }
__device__ __forceinline__ cplx cmul(cplx a, cplx b){
    return {a.re*b.re - a.im*b.im, a.re*b.im + a.im*b.re};
}
__device__ __forceinline__ v2f mk2(float a, float b){ v2f r; r.x = a; r.y = b; return r; }

#define AS 0.5f
#define AP 0.125f
#define CS (4.0f*AS*AS)
#define CP (4.0f*AP*AP)

// principal sqrt for Re(z) > 0 regime; 2 trans ops (sqrt + rsqrt)
__device__ __forceinline__ cplx csqrt_fast(cplx z){
    float r  = sqrtf(z.re*z.re + z.im*z.im);
    float u2 = 0.5f*(r + z.re);
    float iu = frsq(u2);
    float u  = u2*iu;
    float v  = 0.5f*z.im*iu;
    return {u, v};
}

// ---------------- per-point chain state ----------------
struct Chain {
    cplx ns2;      // (n0 sin0)^2
    cplx q_u;      // upper-layer q
    pcplx v0, v1;  // unnormalized field vector (s,p packed)
    v2f  tsq;      // |t|^2-recovery accumulator
    float fs_num, fp_num, fs_den, fp_den;
};

__device__ __forceinline__ void chain_init(Chain& C, cplx ns2, cplx n2_t, float nn2_t){
    C.ns2 = ns2;
    C.q_u = csqrt_fast({n2_t.re - ns2.re, n2_t.im - ns2.im});
    C.fs_num = C.q_u.re;
    C.fp_num = (n2_t.re*C.q_u.re + n2_t.im*C.q_u.im) * frcp(nn2_t);
    C.v0.re = mk2(1.f,1.f); C.v0.im = mk2(0.f,0.f);
    C.v1.re = mk2(0.f,0.f); C.v1.im = mk2(0.f,0.f);
    C.tsq   = mk2(1.f,1.f);
    C.fs_den = 1.f; C.fp_den = 1.f;
}

template<bool PHASE>
__device__ __forceinline__ void chain_step(Chain& C, cplx n2_l, float nn2_l,
                                           cplx n2_u, float nn2_u, float kd2){
    cplx q_l = csqrt_fast({n2_l.re - C.ns2.re, n2_l.im - C.ns2.im});
    float aq2 = q_l.re*q_l.re + q_l.im*q_l.im;
    cplx Ac = cmul(n2_u, q_l);
    cplx Bc = cmul(n2_l, C.q_u);

    pcplx den, dff;
    den.re = mk2(AS*(q_l.re + C.q_u.re), AP*(Ac.re + Bc.re));
    den.im = mk2(AS*(q_l.im + C.q_u.im), AP*(Ac.im + Bc.im));
    dff.re = mk2(AS*(q_l.re - C.q_u.re), AP*(Ac.re - Bc.re));
    dff.im = mk2(AS*(q_l.im - C.q_u.im), AP*(Ac.im - Bc.im));

    v2f f = mk2(CS*aq2, CP*aq2*nn2_l*nn2_u);

    pcplx u0, u1;
    u0.re = den.re*C.v0.re - den.im*C.v0.im + dff.re*C.v1.re - dff.im*C.v1.im;
    u0.im = den.re*C.v0.im + den.im*C.v0.re + dff.re*C.v1.im + dff.im*C.v1.re;
    u1.re = dff.re*C.v0.re - dff.im*C.v0.im + den.re*C.v1.re - den.im*C.v1.im;
    u1.im = dff.re*C.v0.im + dff.im*C.v0.re + den.re*C.v1.im + den.im*C.v1.re;

    if (PHASE){
        float dr2 = kd2*q_l.re;            // 2 Re(delta)
        float di2 = kd2*q_l.im;            // 2 Im(delta)
        float e2  = __expf(di2);           // e^{+2 Im delta}
        float s2  = __sinf(dr2);
        float c2  = __cosf(dr2);
        float pr = e2*c2, pi = -e2*s2;     // e^{-2 i delta}
        C.v0.re = pr*u0.re - pi*u0.im;
        C.v0.im = pr*u0.im + pi*u0.re;
        C.v1 = u1;
        C.tsq = C.tsq * (f*e2);
    } else {
        C.v0 = u0; C.v1 = u1;
        C.tsq = C.tsq * f;
        C.fs_den = q_l.re;
        C.fp_den = (n2_l.re*q_l.re + n2_l.im*q_l.im)*frcp(nn2_l);
    }
    C.q_u = q_l;
}

__device__ __forceinline__ void chain_fin(const Chain& C, float& R, float& T){
    v2f m0 = C.v0.re*C.v0.re + C.v0.im*C.v0.im;
    v2f m1 = C.v1.re*C.v1.re + C.v1.im*C.v1.im;
    v2f iv0 = mk2(frcp(m0.x), frcp(m0.y));
    v2f Rv = m1*iv0;
    v2f fac = mk2(C.fs_num*frcp(C.fs_den), C.fp_num*frcp(C.fp_den));
    v2f Tv = C.tsq*iv0*fac;
    R = 0.5f*(Rv.x + Rv.y);
    T = 0.5f*(Tv.x + Tv.y);
}

// ---------------- stage 1: per (layer, lambda): n^2, |n|^2 ; plus 4*pi*th table ----
__global__ void interp_kernel(const float* __restrict__ wavelengths,
                              const float* __restrict__ fixed_data,
                              const float* __restrict__ dyn_wl,
                              const float* __restrict__ ri,
                              const float* __restrict__ ec,
                              const int*   __restrict__ matdist,
                              const float* __restrict__ th_above,
                              const float* __restrict__ th_unk,
                              const float* __restrict__ th_below,
                              float4* __restrict__ nbuf,
                              float*  __restrict__ tk,
                              int NL, int W, int P, int nFixed, int nAbove)
{
    int tid = blockIdx.x*blockDim.x + threadIdx.x;
    if (tid < NL-2) {
        float th;
        if (tid < nAbove)        th = th_above[tid];
        else if (tid == nAbove)  th = th_unk[0] * 0.001f;
        else                     th = th_below[tid - nAbove - 1];
        tk[tid] = 12.5663706143591729539f * th;   // 4*pi*th
    }
    if (tid >= NL*W) return;
    int l = tid / W;
    int w = tid - l*W;
    float x = wavelengths[w];
    int mat = matdist[l];
    const float *xp, *fn, *fk;
    if (mat < nFixed) {
        xp = fixed_data + (size_t)mat*3*P;
        fn = xp + P;
        fk = xp + 2*P;
    } else {
        xp = dyn_wl; fn = ri; fk = ec;
    }
    float nr, nk;
    if (x <= xp[0])            { nr = fn[0];   nk = fk[0]; }
    else if (x >= xp[P-1])     { nr = fn[P-1]; nk = fk[P-1]; }
    else {
        int lo = 0, hi = P-1;
        while (hi - lo > 1) {
            int mid = (lo + hi) >> 1;
            if (xp[mid] <= x) lo = mid; else hi = mid;
        }
        float t = (x - xp[lo]) / (xp[lo+1] - xp[lo]);
        nr = fn[lo] + t*(fn[lo+1] - fn[lo]);
        nk = fk[lo] + t*(fk[lo+1] - fk[lo]);
    }
    float n2re = nr*nr - nk*nk;
    float n2im = 2.0f*nr*nk;
    float nn2  = nr*nr + nk*nk;
    nbuf[tid] = make_float4(n2re, n2im, nn2, 0.0f);
}

// ---------------- stage 2a: TMM, two angles per thread ----------------
template<int NLC>
__global__ void __launch_bounds__(256)
tmm_pair(const float4* __restrict__ nbuf,
         const float*  __restrict__ tk,
         const float*  __restrict__ wavelengths,
         const float*  __restrict__ angles,
         float* __restrict__ out,
         int NLrt, int W, int A, int halfA)
{
    const int NL = (NLC > 0) ? NLC : NLrt;
    int idx = blockIdx.x*blockDim.x + threadIdx.x;
    int total = halfA*W;
    if (idx >= total) return;
    int w  = idx % W;
    int a0 = idx / W;
    int a1 = a0 + halfA;

    float ilam = frcp(wavelengths[w]);
    float sa = __sinf(angles[a0]);
    float sb = __sinf(angles[a1]);
    float s2a = sa*sa, s2b = sb*sb;

    float4 vamb = nbuf[w];
    cplx ns2a = { vamb.x*s2a, vamb.y*s2a };
    cplx ns2b = { vamb.x*s2b, vamb.y*s2b };

    float4 vt = nbuf[(size_t)(NL-1)*W + w];
    cplx n2_u = {vt.x, vt.y};
    float nn2_u = vt.z;

    Chain Ca, Cb;
    chain_init(Ca, ns2a, n2_u, nn2_u);
    chain_init(Cb, ns2b, n2_u, nn2_u);

    #pragma unroll
    for (int i = NL-2; i >= 1; --i) {
        float4 vl = nbuf[(size_t)i*W + w];
        cplx n2_l = {vl.x, vl.y};
        float nn2_l = vl.z;
        float kd2 = tk[i-1]*ilam;
        chain_step<true>(Ca, n2_l, nn2_l, n2_u, nn2_u, kd2);
        chain_step<true>(Cb, n2_l, nn2_l, n2_u, nn2_u, kd2);
        n2_u = n2_l; nn2_u = nn2_l;
    }
    {
        float4 vl = nbuf[w];
        cplx n2_l = {vl.x, vl.y};
        float nn2_l = vl.z;
        chain_step<false>(Ca, n2_l, nn2_l, n2_u, nn2_u, 0.f);
        chain_step<false>(Cb, n2_l, nn2_l, n2_u, nn2_u, 0.f);
    }

    float Ra, Ta, Rb, Tb;
    chain_fin(Ca, Ra, Ta);
    chain_fin(Cb, Rb, Tb);

    size_t plane = (size_t)A * (size_t)W;
    size_t o0 = (size_t)a0*W + w;
    size_t o1 = (size_t)a1*W + w;
    out[o0] = Ra; out[plane + o0] = Ta; out[2*plane + o0] = 1.0f - Ra - Ta;
    out[o1] = Rb; out[plane + o1] = Tb; out[2*plane + o1] = 1.0f - Rb - Tb;
}

// ---------------- stage 2b: single-point tail (odd A / generic) ----------------
__global__ void __launch_bounds__(256)
tmm_single(const float4* __restrict__ nbuf,
           const float*  __restrict__ tk,
           const float*  __restrict__ wavelengths,
           const float*  __restrict__ angles,
           float* __restrict__ out,
           int NL, int W, int A, int a_base)
{
    int idx = blockIdx.x*blockDim.x + threadIdx.x;
    int total = (A - a_base)*W;
    if (idx >= total) return;
    int w = idx % W;
    int a = a_base + idx / W;

    float ilam = frcp(wavelengths[w]);
    float sa = __sinf(angles[a]);
    float s2a = sa*sa;

    float4 vamb = nbuf[w];
    cplx ns2 = { vamb.x*s2a, vamb.y*s2a };

    float4 vt = nbuf[(size_t)(NL-1)*W + w];
    cplx n2_u = {vt.x, vt.y};
    float nn2_u = vt.z;

    Chain C;
    chain_init(C, ns2, n2_u, nn2_u);

    for (int i = NL-2; i >= 1; --i) {
        float4 vl = nbuf[(size_t)i*W + w];
        cplx n2_l = {vl.x, vl.y};
        float nn2_l = vl.z;
        float kd2 = tk[i-1]*ilam;
        chain_step<true>(C, n2_l, nn2_l, n2_u, nn2_u, kd2);
        n2_u = n2_l; nn2_u = nn2_l;
    }
    {
        float4 vl = nbuf[w];
        chain_step<false>(C, {vl.x, vl.y}, vl.z, n2_u, nn2_u, 0.f);
    }

    float R, T;
    chain_fin(C, R, T);
    size_t plane = (size_t)A * (size_t)W;
    size_t o = (size_t)a*W + w;
    out[o] = R; out[plane + o] = T; out[2*plane + o] = 1.0f - R - T;
}

extern "C" void kernel_launch(void* const* d_in, const int* in_sizes, int n_in,
                              void* d_out, int out_size, void* d_ws, size_t ws_size,
                              hipStream_t stream) {
    const float* ri          = (const float*)d_in[0];
    const float* ec          = (const float*)d_in[1];
    const float* unk         = (const float*)d_in[2];
    const float* fixed_data  = (const float*)d_in[3];
    const float* dyn_wl      = (const float*)d_in[4];
    const int*   matdist     = (const int*)  d_in[5];
    const float* th_above    = (const float*)d_in[6];
    const float* th_below    = (const float*)d_in[7];
    const float* wavelengths = (const float*)d_in[8];
    const float* angles      = (const float*)d_in[9];

    int P      = in_sizes[0];
    int NL     = in_sizes[5];
    int nAbove = in_sizes[6];
    int W      = in_sizes[8];
    int A      = in_sizes[9];
    int nFixed = in_sizes[3] / (3*P);

    float4* nbuf = (float4*)d_ws;                       // [NL][W] {n2.re, n2.im, |n|^2, 0}
    float*  tk   = (float*)((char*)d_ws + (size_t)NL*W*sizeof(float4));  // [NL-2] 4*pi*th

    int tot1 = NL*W;
    interp_kernel<<<(tot1+255)/256, 256, 0, stream>>>(
        wavelengths, fixed_data, dyn_wl, ri, ec, matdist,
        th_above, unk, th_below, nbuf, tk, NL, W, P, nFixed, nAbove);

    int halfA = A >> 1;
    if (halfA > 0) {
        int tot2 = halfA*W;
        int blocks = (tot2+255)/256;
        if (NL == 13) {
            tmm_pair<13><<<blocks, 256, 0, stream>>>(
                nbuf, tk, wavelengths, angles, (float*)d_out, NL, W, A, halfA);
        } else {
            tmm_pair<0><<<blocks, 256, 0, stream>>>(
                nbuf, tk, wavelengths, angles, (float*)d_out, NL, W, A, halfA);
        }
    }
    if (A & 1) {
        int a_base = halfA*2;
        int tot3 = (A - a_base)*W;
        tmm_single<<<(tot3+255)/256, 256, 0, stream>>>(
            nbuf, tk, wavelengths, angles, (float*)d_out, NL, W, A, a_base);
    }
}